// Round 1
// baseline (5716.156 us; speedup 1.0000x reference)
//
#include <hip/hip_runtime.h>
#include <cstdint>
#include <cstddef>

typedef __attribute__((ext_vector_type(8))) short short8;
typedef __attribute__((ext_vector_type(4))) float f32x4;
typedef __attribute__((ext_vector_type(4))) unsigned int u32x4;

#define NEG_LOG2E -1.44269504088896340736f
#define MFMA_BF16 __builtin_amdgcn_mfma_f32_16x16x32_bf16

// ---- helpers -------------------------------------------------------------
static __device__ __forceinline__ unsigned int cvt_pk_bf16(float lo, float hi) {
  unsigned int r;
  asm("v_cvt_pk_bf16_f32 %0, %1, %2" : "=v"(r) : "v"(lo), "v"(hi));
  return r;
}
// xs is pre-scaled by -log2(e): returns sigmoid(x_true)
static __device__ __forceinline__ float sigmoid_scaled(float xs) {
  return __builtin_amdgcn_rcpf(1.0f + __builtin_amdgcn_exp2f(xs));
}

// ===========================================================================
// Kernel 1: repack w_rec (fp32 [1024][256]) -> bf16 fragment buffer, scaled
// by -log2(e).  Frag f = ct*8 + kt, layout [f][lane 0..63][8 bf16]:
// lane l holds w'[ct*16 + (l&15)][kt*32 + (l>>4)*8 + e]  (MFMA B-operand).
// ===========================================================================
__global__ void wfrag_setup(const float* __restrict__ w_rec,
                            unsigned short* __restrict__ wf) {
  const int f = blockIdx.x;   // 0..511
  const int l = threadIdx.x;  // 0..63
  const int ct = f >> 3, kt = f & 7;
  const float* src = w_rec + (size_t)(ct * 16 + (l & 15)) * 256 + kt * 32 + (l >> 4) * 8;
  u32x4 ov;
#pragma unroll
  for (int e = 0; e < 4; ++e)
    ov[e] = cvt_pk_bf16(src[2 * e] * NEG_LOG2E, src[2 * e + 1] * NEG_LOG2E);
  *(u32x4*)(wf + (size_t)f * 512 + (size_t)l * 8) = ov;
}

// ===========================================================================
// Kernel 2: gx = (x @ w_in^T + b) * -log2(e), written as bf16 packed in the
// EXACT layout the RNN consumes:
//   dword[ ((t*16 + bg)*32 + p)*64 + lane ] = bf16(ct=2p) | bf16(ct=2p+1)<<16
// where for (t, b=bg*4+bl, col): lane = bl*16 + (col&15), p = (col>>4)>>1.
// 128x128 tile, 4 waves, K=256, operands loaded straight from global fp32.
// ===========================================================================
static __device__ __forceinline__ short8 ldcvt8(const float* p) {
  f32x4 v0 = *(const f32x4*)p;
  f32x4 v1 = *(const f32x4*)(p + 4);
  u32x4 u;
  u[0] = cvt_pk_bf16(v0[0], v0[1]);
  u[1] = cvt_pk_bf16(v0[2], v0[3]);
  u[2] = cvt_pk_bf16(v1[0], v1[1]);
  u[3] = cvt_pk_bf16(v1[2], v1[3]);
  return __builtin_bit_cast(short8, u);
}

__global__ __launch_bounds__(256) void gemm_gx(const float* __restrict__ x,
                                               const float* __restrict__ w_in,
                                               const float* __restrict__ bias,
                                               unsigned int* __restrict__ gx) {
  const int l = threadIdx.x & 63, wid = threadIdx.x >> 6;
  const int mq = wid >> 1, nq = wid & 1;
  const int mbase = blockIdx.x * 128 + mq * 64;
  const int nbase = blockIdx.y * 128 + nq * 64;
  const int lr = l & 15;
  const int lk = (l >> 4) * 8;

  f32x4 acc[4][4] = {};
#pragma unroll
  for (int kt = 0; kt < 8; ++kt) {
    const int k0 = kt * 32 + lk;
    short8 af[4], bf[4];
#pragma unroll
    for (int mt = 0; mt < 4; ++mt)
      af[mt] = ldcvt8(x + (size_t)(mbase + mt * 16 + lr) * 256 + k0);
#pragma unroll
    for (int nt = 0; nt < 4; ++nt)
      bf[nt] = ldcvt8(w_in + (size_t)(nbase + nt * 16 + lr) * 256 + k0);
#pragma unroll
    for (int mt = 0; mt < 4; ++mt)
#pragma unroll
      for (int nt = 0; nt < 4; ++nt)
        acc[mt][nt] = MFMA_BF16(af[mt], bf[nt], acc[mt][nt], 0, 0, 0);
  }

  float bv[4];
#pragma unroll
  for (int nt = 0; nt < 4; ++nt) bv[nt] = bias[nbase + nt * 16 + lr];

#pragma unroll
  for (int mt = 0; mt < 4; ++mt) {
    const int m0 = mbase + mt * 16;                 // 16-aligned
    const int tt = m0 >> 6;                         // chunk-local t
    const int bg = ((m0 & 63) >> 2) + (l >> 4);     // = mt*4 + (l>>4)
#pragma unroll
    for (int ntp = 0; ntp < 2; ++ntp) {
      const int p = (nbase >> 5) + ntp;             // ct-pair index 0..31
#pragma unroll
      for (int r = 0; r < 4; ++r) {
        float e0 = (acc[mt][ntp * 2 + 0][r] + bv[ntp * 2 + 0]) * NEG_LOG2E;
        float e1 = (acc[mt][ntp * 2 + 1][r] + bv[ntp * 2 + 1]) * NEG_LOG2E;
        gx[(((size_t)tt * 16 + bg) * 32 + p) * 64 + (r * 16 + lr)] =
            cvt_pk_bf16(e0, e1);
      }
    }
  }
}

// ===========================================================================
// Kernel 3: the sequential scan.  16 blocks (bg = 4 batches each), 4 waves.
// All weights resident per CU: 96 frags/wave in VGPR/AGPR (384 regs) +
// 32 frags/wave (jidx==3) in LDS (128 KB).  Batches sit in MFMA rows
// {0,4,8,12} so acc element 0 carries all live data across 64 lanes.
// Wave w owns h-coltiles jts = {2w, 2w+1, 2w+8, 2w+9}; gate g of tile jt is
// gate-coltile ct = jt + 16g, so i/o/z/f of a column meet in one wave and c
// never leaves registers.  h ping-pongs through 2x2176B LDS with ONE raw
// s_barrier per step; gx for step t+1 prefetched into regs one step ahead
// (raw barrier => no vmcnt drain => latency fully hidden).
// ===========================================================================
#define HB_ROW 544                      // 512B data + 32B pad (bank spread)
#define HB_SZ (4 * HB_ROW)              // 2176
#define LDSW_SZ (128 * 1024)
#define LDS_TOTAL (LDSW_SZ + 2 * HB_SZ) // 135424

__global__ __launch_bounds__(256, 1) void rnn_scan(
    const unsigned short* __restrict__ wf, const unsigned int* __restrict__ gx,
    float* __restrict__ out, float* __restrict__ hstate,
    float* __restrict__ cstate, int first) {
  extern __shared__ char lds[];
  char* ldsW = lds;
  char* hb0 = lds + LDSW_SZ;
  char* hb1 = hb0 + HB_SZ;

  const int l = threadIdx.x & 63;
  const int w = threadIdx.x >> 6;
  const int bg = blockIdx.x;      // 0..15 -> batches 4bg..4bg+3
  const int bloc = l >> 4;        // local batch 0..3
  const int col = l & 15;
  const int jts[4] = {2 * w, 2 * w + 1, 2 * w + 8, 2 * w + 9};

  // ---- prologue: weights to VGPR (jidx 0..2) -----------------------------
  short8 wv[96];
#pragma unroll
  for (int q = 0; q < 96; ++q) {
    const int jidx = q >> 5, g = (q >> 3) & 3, kt = q & 7;
    const int fidx = (jts[jidx] + 16 * g) * 8 + kt;
    wv[q] = *(const short8*)(wf + (size_t)fidx * 512 + (size_t)l * 8);
  }
  // ---- weights to LDS (jidx == 3), pre-swizzled lane-linear --------------
#pragma unroll
  for (int s = 0; s < 32; ++s) {
    const int g = s >> 3, kt = s & 7;
    const int fidx = (jts[3] + 16 * g) * 8 + kt;
    *(short8*)(ldsW + (size_t)((w * 32 + s) << 10) + l * 16) =
        *(const short8*)(wf + (size_t)fidx * 512 + (size_t)l * 8);
  }

  // ---- h / c init ---------------------------------------------------------
  float carr[4];
  if (first) {
    for (int i = threadIdx.x; i < (2 * HB_SZ) / 4; i += 256)
      ((unsigned int*)hb0)[i] = 0u;
#pragma unroll
    for (int j = 0; j < 4; ++j) carr[j] = 0.0f;
  } else {
#pragma unroll
    for (int jidx = 0; jidx < 4; ++jidx) {
      const int jt = jts[jidx];
      const size_t idx = (size_t)(bg * 4 + bloc) * 256 + jt * 16 + col;
      carr[jidx] = cstate[idx];
      const float hv = hstate[idx];
      *(unsigned short*)(hb0 + bloc * HB_ROW + (jt * 16 + col) * 2) =
          (unsigned short)cvt_pk_bf16(hv, hv);
    }
  }

  // ---- prefetch gx(t=0) ----------------------------------------------------
  unsigned int gxA[8], gxB[8];
  {
    const unsigned int* g0 = gx + (size_t)bg * 2048 + l;
#pragma unroll
    for (int g = 0; g < 4; ++g) {
      gxA[g] = g0[(w + 8 * g) * 64];        // jt pair {2w,2w+1}, gate g
      gxA[4 + g] = g0[(w + 4 + 8 * g) * 64];// jt pair {2w+8,2w+9}, gate g
    }
  }
  __syncthreads();

  float* outp = out + (size_t)(bg * 4 + bloc) * 256 + col;
  const int aoff = ((l & 15) >> 2) * HB_ROW + (l >> 4) * 16;  // A-frag read
  const int hwoff = bloc * HB_ROW;

  auto STEP = [&](int t, char* hbR, char* hbW, unsigned int(&gxC)[8],
                  unsigned int(&gxN)[8]) {
    // issue next-step gx prefetch (stays in flight across the raw barrier)
    const int tn = (t + 1 < 512) ? (t + 1) : 511;
    const unsigned int* gn = gx + (size_t)tn * 32768 + (size_t)bg * 2048 + l;
#pragma unroll
    for (int g = 0; g < 4; ++g) {
      gxN[g] = gn[(w + 8 * g) * 64];
      gxN[4 + g] = gn[(w + 4 + 8 * g) * 64];
    }
    __builtin_amdgcn_sched_barrier(0);

    const char* hrd = hbR + aoff;
#pragma unroll
    for (int jidx = 0; jidx < 4; ++jidx) {
      const int jt = jts[jidx];
      f32x4 a0 = {0.f, 0.f, 0.f, 0.f}, a1 = a0, a2 = a0, a3 = a0;
      if (jidx < 3) {
#pragma unroll
        for (int kt = 0; kt < 8; ++kt) {
          const short8 af = *(const short8*)(hrd + kt * 64);
          a0 = MFMA_BF16(af, wv[jidx * 32 + kt], a0, 0, 0, 0);
          a1 = MFMA_BF16(af, wv[jidx * 32 + 8 + kt], a1, 0, 0, 0);
          a2 = MFMA_BF16(af, wv[jidx * 32 + 16 + kt], a2, 0, 0, 0);
          a3 = MFMA_BF16(af, wv[jidx * 32 + 24 + kt], a3, 0, 0, 0);
        }
      } else {
#pragma unroll
        for (int kt = 0; kt < 8; ++kt) {
          const short8 af = *(const short8*)(hrd + kt * 64);
          const char* wb = ldsW + (size_t)((w * 32 + kt) << 10) + l * 16;
          a0 = MFMA_BF16(af, *(const short8*)(wb), a0, 0, 0, 0);
          a1 = MFMA_BF16(af, *(const short8*)(wb + (8 << 10)), a1, 0, 0, 0);
          a2 = MFMA_BF16(af, *(const short8*)(wb + (16 << 10)), a2, 0, 0, 0);
          a3 = MFMA_BF16(af, *(const short8*)(wb + (24 << 10)), a3, 0, 0, 0);
        }
      }
      // ---- epilogue for this h-coltile ----
      const int base = (jidx >> 1) * 4;
      const bool hi = (jidx & 1) != 0;  // odd jt -> hi half of packed dword
      const float g0f = hi ? __uint_as_float(gxC[base + 0] & 0xffff0000u)
                           : __uint_as_float(gxC[base + 0] << 16);
      const float g1f = hi ? __uint_as_float(gxC[base + 1] & 0xffff0000u)
                           : __uint_as_float(gxC[base + 1] << 16);
      const float g2f = hi ? __uint_as_float(gxC[base + 2] & 0xffff0000u)
                           : __uint_as_float(gxC[base + 2] << 16);
      const float g3f = hi ? __uint_as_float(gxC[base + 3] & 0xffff0000u)
                           : __uint_as_float(gxC[base + 3] << 16);
      const float gi = sigmoid_scaled(a0[0] + g0f);
      const float go = sigmoid_scaled(a1[0] + g1f);
      const float gz = sigmoid_scaled(a2[0] + g2f);
      const float gf = sigmoid_scaled(a3[0] + g3f);
      carr[jidx] = gf * carr[jidx] + (gz - gi);
      const float hs = sigmoid_scaled(carr[jidx] * NEG_LOG2E);
      const float hn = hs - go;
      outp[(size_t)t * 16384 + jt * 16] = hn;
      *(unsigned short*)(hbW + hwoff + (jt * 16 + col) * 2) =
          (unsigned short)cvt_pk_bf16(hn, hn);
    }
    // raw barrier: only LDS drained; gx prefetch stays outstanding
    __builtin_amdgcn_sched_barrier(0);
    asm volatile("s_waitcnt lgkmcnt(0)" ::: "memory");
    __builtin_amdgcn_s_barrier();
    __builtin_amdgcn_sched_barrier(0);
  };

  for (int tt = 0; tt < 256; ++tt) {
    STEP(2 * tt, hb0, hb1, gxA, gxB);
    STEP(2 * tt + 1, hb1, hb0, gxB, gxA);
  }

  // ---- save state for next chunk (h handoff via bf16 == in-chunk path) ----
#pragma unroll
  for (int jidx = 0; jidx < 4; ++jidx) {
    const int jt = jts[jidx];
    const size_t idx = (size_t)(bg * 4 + bloc) * 256 + jt * 16 + col;
    const unsigned short hb =
        *(const unsigned short*)(hb0 + hwoff + (jt * 16 + col) * 2);
    hstate[idx] = __uint_as_float((unsigned int)hb << 16);
    cstate[idx] = carr[jidx];
  }
}

// ===========================================================================
// Host launcher.  ws layout:
//   [0,512K)        wfrag bf16
//   [512K,576K)     hstate fp32 [64][256]
//   [576K,640K)     cstate fp32 [64][256]
//   [1M, 1M+64M)    gx chunk (512 steps, bf16-packed dwords)
// 4 chunks of 512 steps: gemm then scan, state carried in ws.
// ===========================================================================
extern "C" void kernel_launch(void* const* d_in, const int* in_sizes, int n_in,
                              void* d_out, int out_size, void* d_ws,
                              size_t ws_size, hipStream_t stream) {
  const float* x = (const float*)d_in[0];     // [2048][64][256]
  const float* w_in = (const float*)d_in[1];  // [1024][256]
  const float* bias = (const float*)d_in[2];  // [1024]
  const float* wrec = (const float*)d_in[3];  // [1024][256]
  float* out = (float*)d_out;                 // [2048][64][256]
  char* ws = (char*)d_ws;

  unsigned short* wf = (unsigned short*)ws;
  float* hstate = (float*)(ws + (512 << 10));
  float* cstate = (float*)(ws + (576 << 10));
  unsigned int* gxb = (unsigned int*)(ws + (1 << 20));

  (void)in_sizes; (void)n_in; (void)out_size; (void)ws_size;

  hipFuncSetAttribute((const void*)rnn_scan,
                      hipFuncAttributeMaxDynamicSharedMemorySize, LDS_TOTAL);

  wfrag_setup<<<dim3(512), dim3(64), 0, stream>>>(wrec, wf);

  for (int c = 0; c < 4; ++c) {
    const size_t xoff = (size_t)c * 512 * 64 * 256;
    gemm_gx<<<dim3(256, 8), dim3(256), 0, stream>>>(x + xoff, w_in, bias, gxb);
    rnn_scan<<<dim3(16), dim3(256), LDS_TOTAL, stream>>>(
        wf, gxb, out + xoff, hstate, cstate, (c == 0) ? 1 : 0);
  }
}

// Round 4
// 5409.515 us; speedup vs baseline: 1.0567x; 1.0567x over previous
//
#include <hip/hip_runtime.h>
#include <cstdint>
#include <cstddef>

typedef __attribute__((ext_vector_type(8))) short short8;
typedef __attribute__((ext_vector_type(4))) float f32x4;
typedef __attribute__((ext_vector_type(4))) unsigned int u32x4;

#define NEG_LOG2E -1.44269504088896340736f
#define MFMA_BF16 __builtin_amdgcn_mfma_f32_16x16x32_bf16

// ---- helpers -------------------------------------------------------------
static __device__ __forceinline__ unsigned int cvt_pk_bf16(float lo, float hi) {
  unsigned int r;
  asm("v_cvt_pk_bf16_f32 %0, %1, %2" : "=v"(r) : "v"(lo), "v"(hi));
  return r;
}
// xs is pre-scaled by -log2(e): returns sigmoid(x_true)
static __device__ __forceinline__ float sigmoid_scaled(float xs) {
  return __builtin_amdgcn_rcpf(1.0f + __builtin_amdgcn_exp2f(xs));
}
// MFMA with B operand in AGPR.  b MUST already be AGPR-class (born via "=a"
// load) so no copy is inserted.  Callers handle hazards: >=2 cycles between
// VALU write of c and first call (s_nop 1), >=20 cycles between last call and
// any VALU read of c (s_nop fence), both pinned with sched_barrier(0).
static __device__ __forceinline__ f32x4 mfma_ab(short8 a, short8 b, f32x4 c) {
  asm("v_mfma_f32_16x16x32_bf16 %0, %1, %2, %0"
      : "+v"(c)
      : "v"(a), "a"(b));
  return c;
}

// ===========================================================================
// Kernel 1: repack w_rec (fp32 [1024][256]) -> bf16 fragment buffer, scaled
// by -log2(e).  512 frag slots of 1 KB; slot f, lane l, elems e0..7 hold the
// MFMA B-operand fragment: w'[ct*16 + (l&15)][kt*32 + (l>>4)*8 + e].
// Slot layout (w = wave 0..3 of rnn_scan):
//   f = w*64 + q,        q=0..63 : jt = 2w + (q>>5), g=(q>>3)&3, kt=q&7  (AGPR)
//   f = 256 + w*32 + q,  q=0..31 : jt = 2w + 8,      g=q>>3,     kt=q&7  (VGPR)
//   f = 384 + w*32 + q,  q=0..31 : jt = 2w + 9,      g=q>>3,     kt=q&7  (LDS)
// where ct = jt + 16g.
// ===========================================================================
__global__ void wfrag_setup(const float* __restrict__ w_rec,
                            unsigned short* __restrict__ wf) {
  const int f = blockIdx.x;   // 0..511
  const int l = threadIdx.x;  // 0..63
  int jt, g, kt;
  if (f < 256) {
    const int w = f >> 6, q = f & 63;
    jt = 2 * w + (q >> 5); g = (q >> 3) & 3; kt = q & 7;
  } else if (f < 384) {
    const int r = f - 256; const int w = r >> 5, q = r & 31;
    jt = 2 * w + 8; g = q >> 3; kt = q & 7;
  } else {
    const int r = f - 384; const int w = r >> 5, q = r & 31;
    jt = 2 * w + 9; g = q >> 3; kt = q & 7;
  }
  const int ct = jt + 16 * g;
  const float* src = w_rec + (size_t)(ct * 16 + (l & 15)) * 256 + kt * 32 + (l >> 4) * 8;
  u32x4 ov;
#pragma unroll
  for (int e = 0; e < 4; ++e)
    ov[e] = cvt_pk_bf16(src[2 * e] * NEG_LOG2E, src[2 * e + 1] * NEG_LOG2E);
  *(u32x4*)(wf + (size_t)f * 512 + (size_t)l * 8) = ov;
}

// ===========================================================================
// Kernel 2: gx = (x @ w_in^T + b) * -log2(e), written as bf16 packed in the
// EXACT layout the RNN consumes:
//   dword[ ((t*16 + bg)*32 + p)*64 + lane ] = bf16(ct=2p) | bf16(ct=2p+1)<<16
// where for (t, b=bg*4+bl, col): lane = bl*16 + (col&15), p = (col>>4)>>1.
// 128x128 tile, 4 waves, K=256, operands loaded straight from global fp32.
// ===========================================================================
static __device__ __forceinline__ short8 ldcvt8(const float* p) {
  f32x4 v0 = *(const f32x4*)p;
  f32x4 v1 = *(const f32x4*)(p + 4);
  u32x4 u;
  u[0] = cvt_pk_bf16(v0[0], v0[1]);
  u[1] = cvt_pk_bf16(v0[2], v0[3]);
  u[2] = cvt_pk_bf16(v1[0], v1[1]);
  u[3] = cvt_pk_bf16(v1[2], v1[3]);
  return __builtin_bit_cast(short8, u);
}

__global__ __launch_bounds__(256) void gemm_gx(const float* __restrict__ x,
                                               const float* __restrict__ w_in,
                                               const float* __restrict__ bias,
                                               unsigned int* __restrict__ gx) {
  const int l = threadIdx.x & 63, wid = threadIdx.x >> 6;
  const int mq = wid >> 1, nq = wid & 1;
  const int mbase = blockIdx.x * 128 + mq * 64;
  const int nbase = blockIdx.y * 128 + nq * 64;
  const int lr = l & 15;
  const int lk = (l >> 4) * 8;

  f32x4 acc[4][4] = {};
#pragma unroll
  for (int kt = 0; kt < 8; ++kt) {
    const int k0 = kt * 32 + lk;
    short8 af[4], bf[4];
#pragma unroll
    for (int mt = 0; mt < 4; ++mt)
      af[mt] = ldcvt8(x + (size_t)(mbase + mt * 16 + lr) * 256 + k0);
#pragma unroll
    for (int nt = 0; nt < 4; ++nt)
      bf[nt] = ldcvt8(w_in + (size_t)(nbase + nt * 16 + lr) * 256 + k0);
#pragma unroll
    for (int mt = 0; mt < 4; ++mt)
#pragma unroll
      for (int nt = 0; nt < 4; ++nt)
        acc[mt][nt] = MFMA_BF16(af[mt], bf[nt], acc[mt][nt], 0, 0, 0);
  }

  float bv[4];
#pragma unroll
  for (int nt = 0; nt < 4; ++nt) bv[nt] = bias[nbase + nt * 16 + lr];

#pragma unroll
  for (int mt = 0; mt < 4; ++mt) {
    const int m0 = mbase + mt * 16;                 // 16-aligned
    const int tt = m0 >> 6;                         // chunk-local t
    const int bg = ((m0 & 63) >> 2) + (l >> 4);     // = mt*4 + (l>>4)
#pragma unroll
    for (int ntp = 0; ntp < 2; ++ntp) {
      const int p = (nbase >> 5) + ntp;             // ct-pair index 0..31
#pragma unroll
      for (int r = 0; r < 4; ++r) {
        float e0 = (acc[mt][ntp * 2 + 0][r] + bv[ntp * 2 + 0]) * NEG_LOG2E;
        float e1 = (acc[mt][ntp * 2 + 1][r] + bv[ntp * 2 + 1]) * NEG_LOG2E;
        gx[(((size_t)tt * 16 + bg) * 32 + p) * 64 + (r * 16 + lr)] =
            cvt_pk_bf16(e0, e1);
      }
    }
  }
}

// ===========================================================================
// Kernel 3: the sequential scan.  16 blocks (bg = 4 batches each), 4 waves.
// All weights resident per CU:
//   jidx 0,1 -> 64 frags/wave BORN in AGPRs ("=a" global_load, 256 AGPRs)
//   jidx 2   -> 32 frags/wave in arch VGPRs (128 regs, intrinsic path)
//   jidx 3   -> 32 frags/wave in LDS (128 KB total, lane-linear)
// Batches sit in MFMA rows {0,4,8,12} (A rows replicated x4) so acc elem 0
// carries all live data.  Wave w owns h-coltiles {2w, 2w+1, 2w+8, 2w+9}; the
// 4 gates of a column meet in one wave so c never leaves registers.  h
// ping-pongs through 2x2176B LDS with ONE raw s_barrier per step; gx(t+1)
// prefetched into regs one step ahead (no vmcnt drain at the barrier).
// A-frags (h) loaded ONCE per step into 8 regs, reused across all 4 coltiles.
// ===========================================================================
#define HB_ROW 544                      // 512B data + 32B pad (bank spread)
#define HB_SZ (4 * HB_ROW)              // 2176
#define LDSW_SZ (128 * 1024)
#define LDS_TOTAL (LDSW_SZ + 2 * HB_SZ) // 135424

// 4 weight-frag loads straight into AGPRs.  Outputs are AGPR-class from
// birth -> later "a" MFMA operands need no copies.
#define LD4A(i)                                                         \
  asm volatile("global_load_dwordx4 %0, %4, off\n\t"                    \
               "global_load_dwordx4 %1, %4, off offset:1024\n\t"        \
               "global_load_dwordx4 %2, %4, off offset:2048\n\t"        \
               "global_load_dwordx4 %3, %4, off offset:3072"            \
               : "=a"(wa[4 * (i)]), "=a"(wa[4 * (i) + 1]),              \
                 "=a"(wa[4 * (i) + 2]), "=a"(wa[4 * (i) + 3])           \
               : "v"(pA + 4096 * (i)))

__global__ __launch_bounds__(256, 1) void rnn_scan(
    const unsigned short* __restrict__ wf, const unsigned int* __restrict__ gx,
    float* __restrict__ out, float* __restrict__ hstate,
    float* __restrict__ cstate, int first) {
  extern __shared__ char lds[];
  char* ldsW = lds;
  char* hb0 = lds + LDSW_SZ;
  char* hb1 = hb0 + HB_SZ;

  const int l = threadIdx.x & 63;
  const int w = threadIdx.x >> 6;
  const int bg = blockIdx.x;      // 0..15 -> batches 4bg..4bg+3
  const int bloc = l >> 4;        // local batch 0..3
  const int col = l & 15;
  const int jts[4] = {2 * w, 2 * w + 1, 2 * w + 8, 2 * w + 9};

  // ---- prologue: weights jidx 0,1 -> AGPRs (64 frags, contiguous region) --
  short8 wa[64];
  {
    const char* pA = (const char*)wf + (size_t)w * 65536 + (size_t)l * 16;
    LD4A(0);  LD4A(1);  LD4A(2);  LD4A(3);
    LD4A(4);  LD4A(5);  LD4A(6);  LD4A(7);
    LD4A(8);  LD4A(9);  LD4A(10); LD4A(11);
    LD4A(12); LD4A(13); LD4A(14); LD4A(15);
    asm volatile("s_waitcnt vmcnt(0)" ::: "memory");
  }
  // ---- weights jidx 2 -> arch VGPRs (32 frags) ---------------------------
  short8 wv[32];
#pragma unroll
  for (int q = 0; q < 32; ++q)
    wv[q] = *(const short8*)(wf + (size_t)(256 + w * 32 + q) * 512 + (size_t)l * 8);
  // ---- weights jidx 3 -> LDS, lane-linear --------------------------------
#pragma unroll
  for (int s = 0; s < 32; ++s)
    *(short8*)(ldsW + (size_t)((w * 32 + s) << 10) + l * 16) =
        *(const short8*)(wf + (size_t)(384 + w * 32 + s) * 512 + (size_t)l * 8);

  // ---- h / c init ---------------------------------------------------------
  float carr[4];
  if (first) {
    for (int i = threadIdx.x; i < (2 * HB_SZ) / 4; i += 256)
      ((unsigned int*)hb0)[i] = 0u;
#pragma unroll
    for (int j = 0; j < 4; ++j) carr[j] = 0.0f;
  } else {
#pragma unroll
    for (int jidx = 0; jidx < 4; ++jidx) {
      const int jt = jts[jidx];
      const size_t idx = (size_t)(bg * 4 + bloc) * 256 + jt * 16 + col;
      carr[jidx] = cstate[idx];
      const float hv = hstate[idx];
      *(unsigned short*)(hb0 + bloc * HB_ROW + (jt * 16 + col) * 2) =
          (unsigned short)cvt_pk_bf16(hv, hv);
    }
  }

  // ---- prefetch gx(t=0) ----------------------------------------------------
  unsigned int gxA[8], gxB[8];
  {
    const unsigned int* g0 = gx + (size_t)bg * 2048 + l;
#pragma unroll
    for (int g = 0; g < 4; ++g) {
      gxA[g] = g0[(w + 8 * g) * 64];        // jt pair {2w,2w+1}, gate g
      gxA[4 + g] = g0[(w + 4 + 8 * g) * 64];// jt pair {2w+8,2w+9}, gate g
    }
  }
  __syncthreads();

  float* outp = out + (size_t)(bg * 4 + bloc) * 256 + col;
  const int aoff = ((l & 15) >> 2) * HB_ROW + (l >> 4) * 16;  // A-frag read
  const int hwoff = bloc * HB_ROW;

  auto STEP = [&](int t, char* hbR, char* hbW, unsigned int(&gxC)[8],
                  unsigned int(&gxN)[8]) {
    // issue next-step gx prefetch (stays in flight across the raw barrier)
    const int tn = (t + 1 < 512) ? (t + 1) : 511;
    const unsigned int* gn = gx + (size_t)tn * 32768 + (size_t)bg * 2048 + l;
#pragma unroll
    for (int g = 0; g < 4; ++g) {
      gxN[g] = gn[(w + 8 * g) * 64];
      gxN[4 + g] = gn[(w + 4 + 8 * g) * 64];
    }
    __builtin_amdgcn_sched_barrier(0);

    // load the step's A-frags ONCE, reuse across all 4 coltiles
    const char* hrd = hbR + aoff;
    short8 af[8];
#pragma unroll
    for (int kt = 0; kt < 8; ++kt)
      af[kt] = *(const short8*)(hrd + kt * 64);

    // shared epilogue: gates -> c,h update -> global out + LDS h write
    auto EPI = [&](int jidx, float s0, float s1, float s2, float s3) {
      const int jt = jts[jidx];
      const int base = (jidx >> 1) * 4;
      const bool hi = (jidx & 1) != 0;  // odd jt -> hi half of packed dword
      const float g0f = hi ? __uint_as_float(gxC[base + 0] & 0xffff0000u)
                           : __uint_as_float(gxC[base + 0] << 16);
      const float g1f = hi ? __uint_as_float(gxC[base + 1] & 0xffff0000u)
                           : __uint_as_float(gxC[base + 1] << 16);
      const float g2f = hi ? __uint_as_float(gxC[base + 2] & 0xffff0000u)
                           : __uint_as_float(gxC[base + 2] << 16);
      const float g3f = hi ? __uint_as_float(gxC[base + 3] & 0xffff0000u)
                           : __uint_as_float(gxC[base + 3] << 16);
      const float gi = sigmoid_scaled(s0 + g0f);
      const float go = sigmoid_scaled(s1 + g1f);
      const float gz = sigmoid_scaled(s2 + g2f);
      const float gf = sigmoid_scaled(s3 + g3f);
      carr[jidx] = gf * carr[jidx] + (gz - gi);
      const float hs = sigmoid_scaled(carr[jidx] * NEG_LOG2E);
      const float hn = hs - go;
      outp[(size_t)t * 16384 + jt * 16] = hn;
      *(unsigned short*)(hbW + hwoff + (jt * 16 + col) * 2) =
          (unsigned short)cvt_pk_bf16(hn, hn);
    };

    // ---- jidx 0,1 : asm MFMA, weights already resident in AGPRs ----
#pragma unroll
    for (int jx = 0; jx < 2; ++jx) {
      f32x4 q0 = {0.f, 0.f, 0.f, 0.f}, q1 = q0, q2 = q0, q3 = q0;
      __builtin_amdgcn_sched_barrier(0);
      asm volatile("s_nop 1" :::);  // VALU zero-init -> MFMA SrcC hazard
#pragma unroll
      for (int kt = 0; kt < 8; ++kt) {
        q0 = mfma_ab(af[kt], wa[jx * 32 + kt],      q0);
        q1 = mfma_ab(af[kt], wa[jx * 32 + 8 + kt],  q1);
        q2 = mfma_ab(af[kt], wa[jx * 32 + 16 + kt], q2);
        q3 = mfma_ab(af[kt], wa[jx * 32 + 24 + kt], q3);
      }
      __builtin_amdgcn_sched_barrier(0);
      asm volatile("s_nop 7\n\ts_nop 7\n\ts_nop 3" :::);  // D -> VALU hazard
      __builtin_amdgcn_sched_barrier(0);
      EPI(jx, q0[0], q1[0], q2[0], q3[0]);
    }

    // ---- jidx 2 : intrinsic MFMA, weights in arch VGPRs ----
    {
      f32x4 a0 = {0.f, 0.f, 0.f, 0.f}, a1 = a0, a2 = a0, a3 = a0;
#pragma unroll
      for (int kt = 0; kt < 8; ++kt) {
        a0 = MFMA_BF16(af[kt], wv[kt], a0, 0, 0, 0);
        a1 = MFMA_BF16(af[kt], wv[8 + kt], a1, 0, 0, 0);
        a2 = MFMA_BF16(af[kt], wv[16 + kt], a2, 0, 0, 0);
        a3 = MFMA_BF16(af[kt], wv[24 + kt], a3, 0, 0, 0);
      }
      EPI(2, a0[0], a1[0], a2[0], a3[0]);
    }
    // ---- jidx 3 : intrinsic MFMA, weights from LDS ----
    {
      f32x4 a0 = {0.f, 0.f, 0.f, 0.f}, a1 = a0, a2 = a0, a3 = a0;
#pragma unroll
      for (int kt = 0; kt < 8; ++kt) {
        const char* wb = ldsW + (size_t)((w * 32 + kt) << 10) + l * 16;
        a0 = MFMA_BF16(af[kt], *(const short8*)(wb), a0, 0, 0, 0);
        a1 = MFMA_BF16(af[kt], *(const short8*)(wb + (8 << 10)), a1, 0, 0, 0);
        a2 = MFMA_BF16(af[kt], *(const short8*)(wb + (16 << 10)), a2, 0, 0, 0);
        a3 = MFMA_BF16(af[kt], *(const short8*)(wb + (24 << 10)), a3, 0, 0, 0);
      }
      EPI(3, a0[0], a1[0], a2[0], a3[0]);
    }

    // raw barrier: only LDS drained; gx prefetch stays outstanding
    __builtin_amdgcn_sched_barrier(0);
    asm volatile("s_waitcnt lgkmcnt(0)" ::: "memory");
    __builtin_amdgcn_s_barrier();
    __builtin_amdgcn_sched_barrier(0);
  };

  for (int tt = 0; tt < 256; ++tt) {
    STEP(2 * tt, hb0, hb1, gxA, gxB);
    STEP(2 * tt + 1, hb1, hb0, gxB, gxA);
  }

  // ---- save state for next chunk (h handoff via bf16 == in-chunk path) ----
#pragma unroll
  for (int jidx = 0; jidx < 4; ++jidx) {
    const int jt = jts[jidx];
    const size_t idx = (size_t)(bg * 4 + bloc) * 256 + jt * 16 + col;
    const unsigned short hb =
        *(const unsigned short*)(hb0 + hwoff + (jt * 16 + col) * 2);
    hstate[idx] = __uint_as_float((unsigned int)hb << 16);
    cstate[idx] = carr[jidx];
  }
}

// ===========================================================================
// Host launcher.  ws layout:
//   [0,512K)        wfrag bf16 (A region 0-255, V region 256-383, L 384-511)
//   [512K,576K)     hstate fp32 [64][256]
//   [576K,640K)     cstate fp32 [64][256]
//   [1M, 1M+64M)    gx chunk (512 steps, bf16-packed dwords)
// 4 chunks of 512 steps: gemm then scan, state carried in ws.
// ===========================================================================
extern "C" void kernel_launch(void* const* d_in, const int* in_sizes, int n_in,
                              void* d_out, int out_size, void* d_ws,
                              size_t ws_size, hipStream_t stream) {
  const float* x = (const float*)d_in[0];     // [2048][64][256]
  const float* w_in = (const float*)d_in[1];  // [1024][256]
  const float* bias = (const float*)d_in[2];  // [1024]
  const float* wrec = (const float*)d_in[3];  // [1024][256]
  float* out = (float*)d_out;                 // [2048][64][256]
  char* ws = (char*)d_ws;

  unsigned short* wf = (unsigned short*)ws;
  float* hstate = (float*)(ws + (512 << 10));
  float* cstate = (float*)(ws + (576 << 10));
  unsigned int* gxb = (unsigned int*)(ws + (1 << 20));

  (void)in_sizes; (void)n_in; (void)out_size; (void)ws_size;

  hipFuncSetAttribute((const void*)rnn_scan,
                      hipFuncAttributeMaxDynamicSharedMemorySize, LDS_TOTAL);

  wfrag_setup<<<dim3(512), dim3(64), 0, stream>>>(wrec, wf);

  for (int c = 0; c < 4; ++c) {
    const size_t xoff = (size_t)c * 512 * 64 * 256;
    gemm_gx<<<dim3(256, 8), dim3(256), 0, stream>>>(x + xoff, w_in, bias, gxb);
    rnn_scan<<<dim3(16), dim3(256), LDS_TOTAL, stream>>>(
        wf, gxb, out + xoff, hstate, cstate, (c == 0) ? 1 : 0);
  }
}

// Round 5
// 5191.760 us; speedup vs baseline: 1.1010x; 1.0419x over previous
//
#include <hip/hip_runtime.h>
#include <cstdint>
#include <cstddef>

typedef __attribute__((ext_vector_type(8))) short short8;
typedef __attribute__((ext_vector_type(4))) float f32x4;
typedef __attribute__((ext_vector_type(4))) unsigned int u32x4;

#define NEG_LOG2E -1.44269504088896340736f
#define MFMA_BF16 __builtin_amdgcn_mfma_f32_16x16x32_bf16

// ---- helpers -------------------------------------------------------------
static __device__ __forceinline__ unsigned int cvt_pk_bf16(float lo, float hi) {
  unsigned int r;
  asm("v_cvt_pk_bf16_f32 %0, %1, %2" : "=v"(r) : "v"(lo), "v"(hi));
  return r;
}
// xs is pre-scaled by -log2(e): returns sigmoid(x_true)
static __device__ __forceinline__ float sigmoid_scaled(float xs) {
  return __builtin_amdgcn_rcpf(1.0f + __builtin_amdgcn_exp2f(xs));
}
// MFMA with B operand in AGPR.  b MUST already be AGPR-class (born via "=a"
// load) so no copy is inserted.  volatile: keeps program order vs the s_nop
// hazard fences (non-volatile asm may be scheduled across volatile s_nops).
// Callers handle hazards: >=2 cyc between VALU write of c and first call,
// >=20 cyc between last call and any VALU read of c (pinned s_nop fences).
static __device__ __forceinline__ f32x4 mfma_ab(short8 a, short8 b, f32x4 c) {
  asm volatile("v_mfma_f32_16x16x32_bf16 %0, %1, %2, %0"
               : "+v"(c)
               : "v"(a), "a"(b));
  return c;
}

// ===========================================================================
// Kernel 1: repack w_rec (fp32 [1024][256]) -> bf16 fragment buffer, scaled
// by -log2(e).  512 frag slots of 1 KB; slot f, lane l, elems e0..7 hold the
// MFMA B-operand fragment: w'[ct*16 + (l&15)][kt*32 + (l>>4)*8 + e].
// Slot layout (w = wave 0..3 of rnn_scan):
//   f = w*64 + q,        q=0..63 : jt = 2w + (q>>5), g=(q>>3)&3, kt=q&7  (AGPR)
//   f = 256 + w*32 + q,  q=0..31 : jt = 2w + 8,      g=q>>3,     kt=q&7  (VGPR)
//   f = 384 + w*32 + q,  q=0..31 : jt = 2w + 9,      g=q>>3,     kt=q&7  (LDS)
// where ct = jt + 16g.
// ===========================================================================
__global__ void wfrag_setup(const float* __restrict__ w_rec,
                            unsigned short* __restrict__ wf) {
  const int f = blockIdx.x;   // 0..511
  const int l = threadIdx.x;  // 0..63
  int jt, g, kt;
  if (f < 256) {
    const int w = f >> 6, q = f & 63;
    jt = 2 * w + (q >> 5); g = (q >> 3) & 3; kt = q & 7;
  } else if (f < 384) {
    const int r = f - 256; const int w = r >> 5, q = r & 31;
    jt = 2 * w + 8; g = q >> 3; kt = q & 7;
  } else {
    const int r = f - 384; const int w = r >> 5, q = r & 31;
    jt = 2 * w + 9; g = q >> 3; kt = q & 7;
  }
  const int ct = jt + 16 * g;
  const float* src = w_rec + (size_t)(ct * 16 + (l & 15)) * 256 + kt * 32 + (l >> 4) * 8;
  u32x4 ov;
#pragma unroll
  for (int e = 0; e < 4; ++e)
    ov[e] = cvt_pk_bf16(src[2 * e] * NEG_LOG2E, src[2 * e + 1] * NEG_LOG2E);
  *(u32x4*)(wf + (size_t)f * 512 + (size_t)l * 8) = ov;
}

// ===========================================================================
// Kernel 2: gx = (x @ w_in^T + b) * -log2(e), written as bf16 packed in the
// EXACT layout the RNN consumes:
//   dword[ ((t*16 + bg)*32 + p)*64 + lane ] = bf16(ct=2p) | bf16(ct=2p+1)<<16
// where for (t, b=bg*4+bl, col): lane = bl*16 + (col&15), p = (col>>4)>>1.
// 128x128 tile, 4 waves, K=256, operands loaded straight from global fp32.
// ===========================================================================
static __device__ __forceinline__ short8 ldcvt8(const float* p) {
  f32x4 v0 = *(const f32x4*)p;
  f32x4 v1 = *(const f32x4*)(p + 4);
  u32x4 u;
  u[0] = cvt_pk_bf16(v0[0], v0[1]);
  u[1] = cvt_pk_bf16(v0[2], v0[3]);
  u[2] = cvt_pk_bf16(v1[0], v1[1]);
  u[3] = cvt_pk_bf16(v1[2], v1[3]);
  return __builtin_bit_cast(short8, u);
}

__global__ __launch_bounds__(256) void gemm_gx(const float* __restrict__ x,
                                               const float* __restrict__ w_in,
                                               const float* __restrict__ bias,
                                               unsigned int* __restrict__ gx) {
  const int l = threadIdx.x & 63, wid = threadIdx.x >> 6;
  const int mq = wid >> 1, nq = wid & 1;
  const int mbase = blockIdx.x * 128 + mq * 64;
  const int nbase = blockIdx.y * 128 + nq * 64;
  const int lr = l & 15;
  const int lk = (l >> 4) * 8;

  f32x4 acc[4][4] = {};
#pragma unroll
  for (int kt = 0; kt < 8; ++kt) {
    const int k0 = kt * 32 + lk;
    short8 af[4], bf[4];
#pragma unroll
    for (int mt = 0; mt < 4; ++mt)
      af[mt] = ldcvt8(x + (size_t)(mbase + mt * 16 + lr) * 256 + k0);
#pragma unroll
    for (int nt = 0; nt < 4; ++nt)
      bf[nt] = ldcvt8(w_in + (size_t)(nbase + nt * 16 + lr) * 256 + k0);
#pragma unroll
    for (int mt = 0; mt < 4; ++mt)
#pragma unroll
      for (int nt = 0; nt < 4; ++nt)
        acc[mt][nt] = MFMA_BF16(af[mt], bf[nt], acc[mt][nt], 0, 0, 0);
  }

  float bv[4];
#pragma unroll
  for (int nt = 0; nt < 4; ++nt) bv[nt] = bias[nbase + nt * 16 + lr];

#pragma unroll
  for (int mt = 0; mt < 4; ++mt) {
    const int m0 = mbase + mt * 16;                 // 16-aligned
    const int tt = m0 >> 6;                         // chunk-local t
    const int bg = ((m0 & 63) >> 2) + (l >> 4);     // = mt*4 + (l>>4)
#pragma unroll
    for (int ntp = 0; ntp < 2; ++ntp) {
      const int p = (nbase >> 5) + ntp;             // ct-pair index 0..31
#pragma unroll
      for (int r = 0; r < 4; ++r) {
        float e0 = (acc[mt][ntp * 2 + 0][r] + bv[ntp * 2 + 0]) * NEG_LOG2E;
        float e1 = (acc[mt][ntp * 2 + 1][r] + bv[ntp * 2 + 1]) * NEG_LOG2E;
        gx[(((size_t)tt * 16 + bg) * 32 + p) * 64 + (r * 16 + lr)] =
            cvt_pk_bf16(e0, e1);
      }
    }
  }
}

// ===========================================================================
// Kernel 3: the sequential scan.  16 blocks (bg = 4 batches each), 4 waves.
// All weights resident per CU:
//   jidx 0,1 -> 64 frags/wave BORN in AGPRs ("=a" global_load, 256 AGPRs)
//   jidx 2   -> 32 frags/wave in arch VGPRs (128 regs, intrinsic path)
//   jidx 3   -> 32 frags/wave in LDS (128 KB total, lane-linear)
// Step structure (one raw s_barrier per step, NO vmcnt drain -- the
// per-step waitcnt asm deliberately has no "memory" clobber so the gx
// prefetch loads and out stores stay in flight across the barrier):
//   region A: gx(t+1) prefetch issue; af (h) ds_reads; 64 asm MFMAs
//   fence:    s_nop x20 (asm-MFMA D -> VALU hazard), pinned both sides
//   region B: EPI(0..1) VALU interleaved by compiler with jidx2/3
//             intrinsic MFMAs + LDS weight reads; EPI(2..3)
//   barrier:  s_waitcnt lgkmcnt(0); s_barrier   (LDS-only drain)
// ===========================================================================
#define HB_ROW 544                      // 512B data + 32B pad (bank spread)
#define HB_SZ (4 * HB_ROW)              // 2176
#define LDSW_SZ (128 * 1024)
#define LDS_TOTAL (LDSW_SZ + 2 * HB_SZ) // 135424

// 4 weight-frag loads straight into AGPRs.  Outputs are AGPR-class from
// birth -> later "a" MFMA operands need no copies.
#define LD4A(i)                                                         \
  asm volatile("global_load_dwordx4 %0, %4, off\n\t"                    \
               "global_load_dwordx4 %1, %4, off offset:1024\n\t"        \
               "global_load_dwordx4 %2, %4, off offset:2048\n\t"        \
               "global_load_dwordx4 %3, %4, off offset:3072"            \
               : "=a"(wa[4 * (i)]), "=a"(wa[4 * (i) + 1]),              \
                 "=a"(wa[4 * (i) + 2]), "=a"(wa[4 * (i) + 3])           \
               : "v"(pA + 4096 * (i)))

__global__ __launch_bounds__(256, 1) void rnn_scan(
    const unsigned short* __restrict__ wf, const unsigned int* __restrict__ gx,
    float* __restrict__ out, float* __restrict__ hstate,
    float* __restrict__ cstate, int first) {
  extern __shared__ char lds[];
  char* ldsW = lds;
  char* hb0 = lds + LDSW_SZ;
  char* hb1 = hb0 + HB_SZ;

  const int l = threadIdx.x & 63;
  const int w = threadIdx.x >> 6;
  const int bg = blockIdx.x;      // 0..15 -> batches 4bg..4bg+3
  const int bloc = l >> 4;        // local batch 0..3
  const int col = l & 15;
  const int jts[4] = {2 * w, 2 * w + 1, 2 * w + 8, 2 * w + 9};

  // ---- prologue: weights jidx 0,1 -> AGPRs (64 frags, contiguous region) --
  short8 wa[64];
  {
    const char* pA = (const char*)wf + (size_t)w * 65536 + (size_t)l * 16;
    LD4A(0);  LD4A(1);  LD4A(2);  LD4A(3);
    LD4A(4);  LD4A(5);  LD4A(6);  LD4A(7);
    LD4A(8);  LD4A(9);  LD4A(10); LD4A(11);
    LD4A(12); LD4A(13); LD4A(14); LD4A(15);
    asm volatile("s_waitcnt vmcnt(0)" ::: "memory");
  }
  // ---- weights jidx 2 -> arch VGPRs (32 frags) ---------------------------
  short8 wv[32];
#pragma unroll
  for (int q = 0; q < 32; ++q)
    wv[q] = *(const short8*)(wf + (size_t)(256 + w * 32 + q) * 512 + (size_t)l * 8);
  // ---- weights jidx 3 -> LDS, lane-linear --------------------------------
#pragma unroll
  for (int s = 0; s < 32; ++s)
    *(short8*)(ldsW + (size_t)((w * 32 + s) << 10) + l * 16) =
        *(const short8*)(wf + (size_t)(384 + w * 32 + s) * 512 + (size_t)l * 8);

  // ---- h / c init ---------------------------------------------------------
  float carr[4];
  if (first) {
    for (int i = threadIdx.x; i < (2 * HB_SZ) / 4; i += 256)
      ((unsigned int*)hb0)[i] = 0u;
#pragma unroll
    for (int j = 0; j < 4; ++j) carr[j] = 0.0f;
  } else {
#pragma unroll
    for (int jidx = 0; jidx < 4; ++jidx) {
      const int jt = jts[jidx];
      const size_t idx = (size_t)(bg * 4 + bloc) * 256 + jt * 16 + col;
      carr[jidx] = cstate[idx];
      const float hv = hstate[idx];
      *(unsigned short*)(hb0 + bloc * HB_ROW + (jt * 16 + col) * 2) =
          (unsigned short)cvt_pk_bf16(hv, hv);
    }
  }

  // ---- prefetch gx(t=0) ----------------------------------------------------
  unsigned int gxA[8], gxB[8];
  {
    const unsigned int* g0 = gx + (size_t)bg * 2048 + l;
#pragma unroll
    for (int g = 0; g < 4; ++g) {
      gxA[g] = g0[(w + 8 * g) * 64];        // jt pair {2w,2w+1}, gate g
      gxA[4 + g] = g0[(w + 4 + 8 * g) * 64];// jt pair {2w+8,2w+9}, gate g
    }
  }
  __syncthreads();

  float* outp = out + (size_t)(bg * 4 + bloc) * 256 + col;
  const int aoff = ((l & 15) >> 2) * HB_ROW + (l >> 4) * 16;  // A-frag read
  const int hwoff = bloc * HB_ROW;

  auto STEP = [&](int t, char* hbR, char* hbW, unsigned int(&gxC)[8],
                  unsigned int(&gxN)[8]) {
    // zero asm-path accumulators early: the prefetch block below provides
    // plenty of distance for the VALU-write -> MFMA-SrcC hazard.
    f32x4 q0 = {0.f, 0.f, 0.f, 0.f}, q1 = q0, q2 = q0, q3 = q0;
    f32x4 q4 = q0, q5 = q0, q6 = q0, q7 = q0;

    // issue next-step gx prefetch (stays in flight across the raw barrier)
    const int tn = (t + 1 < 512) ? (t + 1) : 511;
    const unsigned int* gn = gx + (size_t)tn * 32768 + (size_t)bg * 2048 + l;
#pragma unroll
    for (int g = 0; g < 4; ++g) {
      gxN[g] = gn[(w + 8 * g) * 64];
      gxN[4 + g] = gn[(w + 4 + 8 * g) * 64];
    }

    // load the step's A-frags ONCE, reuse across all 4 coltiles
    const char* hrd = hbR + aoff;
    short8 af[8];
#pragma unroll
    for (int kt = 0; kt < 8; ++kt)
      af[kt] = *(const short8*)(hrd + kt * 64);

    // shared epilogue: gates -> c,h update -> global out + LDS h write
    auto EPI = [&](int jidx, float s0, float s1, float s2, float s3) {
      const int jt = jts[jidx];
      const int base = (jidx >> 1) * 4;
      const bool hi = (jidx & 1) != 0;  // odd jt -> hi half of packed dword
      const float g0f = hi ? __uint_as_float(gxC[base + 0] & 0xffff0000u)
                           : __uint_as_float(gxC[base + 0] << 16);
      const float g1f = hi ? __uint_as_float(gxC[base + 1] & 0xffff0000u)
                           : __uint_as_float(gxC[base + 1] << 16);
      const float g2f = hi ? __uint_as_float(gxC[base + 2] & 0xffff0000u)
                           : __uint_as_float(gxC[base + 2] << 16);
      const float g3f = hi ? __uint_as_float(gxC[base + 3] & 0xffff0000u)
                           : __uint_as_float(gxC[base + 3] << 16);
      const float gi = sigmoid_scaled(s0 + g0f);
      const float go = sigmoid_scaled(s1 + g1f);
      const float gz = sigmoid_scaled(s2 + g2f);
      const float gf = sigmoid_scaled(s3 + g3f);
      carr[jidx] = gf * carr[jidx] + (gz - gi);
      const float hs = sigmoid_scaled(carr[jidx] * NEG_LOG2E);
      const float hn = hs - go;
      outp[(size_t)t * 16384 + jt * 16] = hn;
      *(unsigned short*)(hbW + hwoff + (jt * 16 + col) * 2) =
          (unsigned short)cvt_pk_bf16(hn, hn);
    };

    // ---- region A: jidx 0,1 asm MFMAs (8 independent chains) ----
    __builtin_amdgcn_sched_barrier(0);
    asm volatile("s_nop 1" :::);  // VALU zero-init -> MFMA SrcC hazard
#pragma unroll
    for (int kt = 0; kt < 8; ++kt) {
      q0 = mfma_ab(af[kt], wa[kt],      q0);
      q1 = mfma_ab(af[kt], wa[8 + kt],  q1);
      q2 = mfma_ab(af[kt], wa[16 + kt], q2);
      q3 = mfma_ab(af[kt], wa[24 + kt], q3);
      q4 = mfma_ab(af[kt], wa[32 + kt], q4);
      q5 = mfma_ab(af[kt], wa[40 + kt], q5);
      q6 = mfma_ab(af[kt], wa[48 + kt], q6);
      q7 = mfma_ab(af[kt], wa[56 + kt], q7);
    }
    // fence: asm-MFMA D write -> VALU read hazard (pinned both sides)
    __builtin_amdgcn_sched_barrier(0);
    asm volatile("s_nop 7\n\ts_nop 7\n\ts_nop 3" :::);
    __builtin_amdgcn_sched_barrier(0);

    // ---- region B: EPIs + jidx 2,3 intrinsic MFMAs, compiler-scheduled ----
    EPI(0, q0[0], q1[0], q2[0], q3[0]);
    EPI(1, q4[0], q5[0], q6[0], q7[0]);
    {
      f32x4 a0 = {0.f, 0.f, 0.f, 0.f}, a1 = a0, a2 = a0, a3 = a0;
#pragma unroll
      for (int kt = 0; kt < 8; ++kt) {
        a0 = MFMA_BF16(af[kt], wv[kt], a0, 0, 0, 0);
        a1 = MFMA_BF16(af[kt], wv[8 + kt], a1, 0, 0, 0);
        a2 = MFMA_BF16(af[kt], wv[16 + kt], a2, 0, 0, 0);
        a3 = MFMA_BF16(af[kt], wv[24 + kt], a3, 0, 0, 0);
      }
      EPI(2, a0[0], a1[0], a2[0], a3[0]);
    }
    {
      f32x4 a0 = {0.f, 0.f, 0.f, 0.f}, a1 = a0, a2 = a0, a3 = a0;
#pragma unroll
      for (int kt = 0; kt < 8; ++kt) {
        const char* wb = ldsW + (size_t)((w * 32 + kt) << 10) + l * 16;
        a0 = MFMA_BF16(af[kt], *(const short8*)(wb), a0, 0, 0, 0);
        a1 = MFMA_BF16(af[kt], *(const short8*)(wb + (8 << 10)), a1, 0, 0, 0);
        a2 = MFMA_BF16(af[kt], *(const short8*)(wb + (16 << 10)), a2, 0, 0, 0);
        a3 = MFMA_BF16(af[kt], *(const short8*)(wb + (24 << 10)), a3, 0, 0, 0);
      }
      EPI(3, a0[0], a1[0], a2[0], a3[0]);
    }

    // raw barrier: LDS-only drain (NO "memory" clobber -> no vmcnt(0));
    // gx prefetch loads and out stores stay in flight across the barrier.
    __builtin_amdgcn_sched_barrier(0);
    asm volatile("s_waitcnt lgkmcnt(0)");
    __builtin_amdgcn_s_barrier();
    __builtin_amdgcn_sched_barrier(0);
  };

  for (int tt = 0; tt < 256; ++tt) {
    STEP(2 * tt, hb0, hb1, gxA, gxB);
    STEP(2 * tt + 1, hb1, hb0, gxB, gxA);
  }

  // ---- save state for next chunk (h handoff via bf16 == in-chunk path) ----
#pragma unroll
  for (int jidx = 0; jidx < 4; ++jidx) {
    const int jt = jts[jidx];
    const size_t idx = (size_t)(bg * 4 + bloc) * 256 + jt * 16 + col;
    const unsigned short hb =
        *(const unsigned short*)(hb0 + hwoff + (jt * 16 + col) * 2);
    hstate[idx] = __uint_as_float((unsigned int)hb << 16);
    cstate[idx] = carr[jidx];
  }
}

// ===========================================================================
// Host launcher.  ws layout:
//   [0,512K)        wfrag bf16 (A region 0-255, V region 256-383, L 384-511)
//   [512K,576K)     hstate fp32 [64][256]
//   [576K,640K)     cstate fp32 [64][256]
//   [1M, 1M+64M)    gx chunk (512 steps, bf16-packed dwords)
// 4 chunks of 512 steps: gemm then scan, state carried in ws.
// ===========================================================================
extern "C" void kernel_launch(void* const* d_in, const int* in_sizes, int n_in,
                              void* d_out, int out_size, void* d_ws,
                              size_t ws_size, hipStream_t stream) {
  const float* x = (const float*)d_in[0];     // [2048][64][256]
  const float* w_in = (const float*)d_in[1];  // [1024][256]
  const float* bias = (const float*)d_in[2];  // [1024]
  const float* wrec = (const float*)d_in[3];  // [1024][256]
  float* out = (float*)d_out;                 // [2048][64][256]
  char* ws = (char*)d_ws;

  unsigned short* wf = (unsigned short*)ws;
  float* hstate = (float*)(ws + (512 << 10));
  float* cstate = (float*)(ws + (576 << 10));
  unsigned int* gxb = (unsigned int*)(ws + (1 << 20));

  (void)in_sizes; (void)n_in; (void)out_size; (void)ws_size;

  hipFuncSetAttribute((const void*)rnn_scan,
                      hipFuncAttributeMaxDynamicSharedMemorySize, LDS_TOTAL);

  wfrag_setup<<<dim3(512), dim3(64), 0, stream>>>(wrec, wf);

  for (int c = 0; c < 4; ++c) {
    const size_t xoff = (size_t)c * 512 * 64 * 256;
    gemm_gx<<<dim3(256, 8), dim3(256), 0, stream>>>(x + xoff, w_in, bias, gxb);
    rnn_scan<<<dim3(16), dim3(256), LDS_TOTAL, stream>>>(
        wf, gxb, out + xoff, hstate, cstate, (c == 0) ? 1 : 0);
  }
}